// Round 20
// baseline (218.040 us; speedup 1.0000x reference)
//
#include <hip/hip_runtime.h>
#include <hip/hip_bf16.h>

// Problem constants (B,T,E,H,D) = (4,1024,1024,16,64)
#define BB 4
#define TT 1024
#define EE 1024
#define HH 16
#define DD 64
#define MM 4096    // B*T rows
#define NQKV 3072  // q|k|v packed cols
#define E4 4096    // 4*E

using short8  = __attribute__((ext_vector_type(8))) short;
using short4v = __attribute__((ext_vector_type(4))) short;
using f32x4   = __attribute__((ext_vector_type(4))) float;

__device__ __forceinline__ short f2bf(float f) {
    __hip_bfloat16 h = __float2bfloat16(f);
    return *reinterpret_cast<short*>(&h);
}

__device__ __forceinline__ float bf2f(short s) {
    unsigned int u = ((unsigned int)(unsigned short)s) << 16;
    return __uint_as_float(u);
}

// pack two f32 -> one u32 of 2 bf16 (low = a, high = b); no builtin on gfx950
__device__ __forceinline__ unsigned int cvtpk_bf16(float a, float b) {
    unsigned int w;
    asm("v_cvt_pk_bf16_f32 %0, %1, %2" : "=v"(w) : "v"(a), "v"(b));
    return w;
}

// async global->LDS, 16B per lane. LDS dest is wave-uniform base + lane*16.
__device__ __forceinline__ void gld16(const void* g, void* l) {
    __builtin_amdgcn_global_load_lds((__attribute__((address_space(1))) void*)g,
                                     (__attribute__((address_space(3))) void*)l,
                                     16, 0, 0);
}

// ---------------- fused weight packs (one launch, float4 loads) ----------------
__device__ __forceinline__ void tcvt_tile(const float* __restrict__ in,
                                          short* __restrict__ out,
                                          int R, int C, int r0, int c0,
                                          float scale) {
    __shared__ short tile[64][68];
    const int rr = threadIdx.x >> 4;          // 0..15
    const int c4 = (threadIdx.x & 15) * 4;    // 0..60
#pragma unroll
    for (int i = 0; i < 4; ++i) {
        int r = i * 16 + rr;
        float4 v = *(const float4*)&in[(size_t)(r0 + r) * C + c0 + c4];
        tile[c4 + 0][r] = f2bf(v.x * scale);
        tile[c4 + 1][r] = f2bf(v.y * scale);
        tile[c4 + 2][r] = f2bf(v.z * scale);
        tile[c4 + 3][r] = f2bf(v.w * scale);
    }
    __syncthreads();
#pragma unroll
    for (int i = 0; i < 4; ++i) {
        int c = i * 16 + rr;
        short4v s = *(const short4v*)&tile[c][c4];
        *(short4v*)&out[(size_t)(c0 + c) * R + r0 + c4] = s;
    }
}

__global__ __launch_bounds__(256) void packs_kernel(const float* __restrict__ Wq,
                                                    const float* __restrict__ Wk,
                                                    const float* __restrict__ Wv,
                                                    const float* __restrict__ Wp,
                                                    const float* __restrict__ W1,
                                                    const float* __restrict__ W2,
                                                    short* __restrict__ wqkv,
                                                    short* __restrict__ wp_bf,
                                                    short* __restrict__ w1_bf,
                                                    short* __restrict__ w2_bf) {
    const int blk = blockIdx.x;
    if (blk < 768) {
        const int m = blk >> 4;            // 0..47
        const int which = m >> 4, head = m & 15;
        const float* src = ((which == 0) ? Wq : (which == 1) ? Wk : Wv) +
                           (size_t)head * EE * DD;
        const float scale = (which == 1) ? 1.44269504f : 1.0f;
        const int e0 = (blk & 15) * 64;
        tcvt_tile(src, wqkv + (size_t)(which * 1024 + head * 64) * EE,
                  EE, DD, e0, 0, scale);
    } else if (blk < 1024) {
        const int idx = blk - 768;
        tcvt_tile(Wp, wp_bf, EE, EE, (idx >> 4) * 64, (idx & 15) * 64, 1.0f);
    } else if (blk < 2048) {
        const int idx = blk - 1024;
        tcvt_tile(W1, w1_bf, EE, E4, (idx >> 6) * 64, (idx & 63) * 64, 1.0f);
    } else {
        const int idx = blk - 2048;
        tcvt_tile(W2, w2_bf, E4, EE, (idx >> 4) * 64, (idx & 15) * 64, 1.0f);
    }
}

// ---------------- V transpose: qkv V-part [b*T+t][2048 + c] -> vT[(b*1024+c)][t] ----------------
__global__ __launch_bounds__(256) void vtr_kernel(const short* __restrict__ qkv,
                                                  short* __restrict__ vT) {
    __shared__ short tile[64][68];
    const int b = blockIdx.z;
    const int t0 = blockIdx.x * 64, c0 = blockIdx.y * 64;
    const int tr = threadIdx.x >> 4;          // 0..15
    const int q4 = (threadIdx.x & 15) * 4;    // 0..60
#pragma unroll
    for (int i = 0; i < 4; ++i) {
        int t = i * 16 + tr;
        short4v v = *(const short4v*)&qkv[((size_t)b * TT + t0 + t) * NQKV + 2048 + c0 + q4];
        *(short4v*)&tile[t][q4] = v;
    }
    __syncthreads();
#pragma unroll
    for (int i = 0; i < 4; ++i) {
        int c = i * 16 + tr;
        short4v v;
        v[0] = tile[q4 + 0][c];
        v[1] = tile[q4 + 1][c];
        v[2] = tile[q4 + 2][c];
        v[3] = tile[q4 + 3][c];
        *(short4v*)&vT[((size_t)b * 1024 + c0 + c) * TT + t0 + q4] = v;
    }
}

// ---------------- LayerNorm (fp32 in -> bf16 out) ----------------
__global__ __launch_bounds__(256) void ln_kernel(const float* __restrict__ x,
                                                 const float* __restrict__ g,
                                                 const float* __restrict__ b,
                                                 short* __restrict__ out) {
    __shared__ float red[4];
    const int row = blockIdx.x;
    const int tid = threadIdx.x;
    float4 v = *(const float4*)&x[(size_t)row * EE + tid * 4];
    float s = v.x + v.y + v.z + v.w;
#pragma unroll
    for (int off = 32; off >= 1; off >>= 1) s += __shfl_xor(s, off, 64);
    if ((tid & 63) == 0) red[tid >> 6] = s;
    __syncthreads();
    float mean = (red[0] + red[1] + red[2] + red[3]) * (1.0f / EE);
    __syncthreads();
    float d0 = v.x - mean, d1 = v.y - mean, d2 = v.z - mean, d3 = v.w - mean;
    s = d0 * d0 + d1 * d1 + d2 * d2 + d3 * d3;
#pragma unroll
    for (int off = 32; off >= 1; off >>= 1) s += __shfl_xor(s, off, 64);
    if ((tid & 63) == 0) red[tid >> 6] = s;
    __syncthreads();
    float var = (red[0] + red[1] + red[2] + red[3]) * (1.0f / EE);
    float rstd = rsqrtf(var + 1e-5f);
    int c = tid * 4;
    short4v o;
    o[0] = f2bf(d0 * rstd * g[c + 0] + b[c + 0]);
    o[1] = f2bf(d1 * rstd * g[c + 1] + b[c + 1]);
    o[2] = f2bf(d2 * rstd * g[c + 2] + b[c + 2]);
    o[3] = f2bf(d3 * rstd * g[c + 3] + b[c + 3]);
    *(short4v*)&out[(size_t)row * EE + c] = o;
}

// ---------------- split-K=4 reduce (bf16 partials, 8 elem/thread) ----------------
__global__ __launch_bounds__(256) void redk4_kernel(const short* __restrict__ parts,
                                                    const float* __restrict__ bias,
                                                    const float* __restrict__ resid,
                                                    float* __restrict__ out) {
    const size_t i = ((size_t)blockIdx.x * 256 + threadIdx.x) * 8;
    float4 r0 = *(const float4*)&resid[i];
    float4 r1 = *(const float4*)&resid[i + 4];
    const float* bb = &bias[i & 1023];
    float4 b0 = *(const float4*)&bb[0];
    float4 b1 = *(const float4*)&bb[4];
    float acc[8];
    acc[0] = r0.x + b0.x; acc[1] = r0.y + b0.y;
    acc[2] = r0.z + b0.z; acc[3] = r0.w + b0.w;
    acc[4] = r1.x + b1.x; acc[5] = r1.y + b1.y;
    acc[6] = r1.z + b1.z; acc[7] = r1.w + b1.w;
#pragma unroll
    for (int z = 0; z < 4; ++z) {
        short8 p = *(const short8*)&parts[(size_t)z * MM * EE + i];
#pragma unroll
        for (int j = 0; j < 8; ++j) acc[j] += bf2f(p[j]);
    }
    float4 o0, o1;
    o0.x = acc[0]; o0.y = acc[1]; o0.z = acc[2]; o0.w = acc[3];
    o1.x = acc[4]; o1.y = acc[5]; o1.z = acc[6]; o1.w = acc[7];
    *(float4*)&out[i] = o0;
    *(float4*)&out[i + 4] = o1;
}

// ---------------- 256x256 8-phase bf16 GEMM (T2+T3+T4+T5) ----------------
// Pipelined A-fragment reads: phase p+1's af reads issue right after phase
// p's ENTRY barrier, before p's MFMA cluster (ping-pong afA/afB; buf stable
// for the whole tile — next stageA into buf happens only at tile u+1's p0,
// after this tile's closing barrier). Barriers/stages/vmcnt identical to the
// verified 2-barrier schedule. SPLIT: bf16 partial at outp + z*M*N.
template <bool HAS_BIAS, bool RELU, bool SPLIT>
__global__ __launch_bounds__(512, 2) void gemm256(const short* __restrict__ A,
                                                  const short* __restrict__ Bt,
                                                  const float* __restrict__ bias,
                                                  void* __restrict__ outp,
                                                  int M, int N, int K, int lda) {
    __shared__ __align__(16) short Ab[2][2][8192];   // [buf][half][128*64]
    __shared__ __align__(16) short Bb[2][2][8192];

    const int tid = threadIdx.x;
    const int lane = tid & 63;
    const int wid = tid >> 6;          // 0..7
    const int wr = wid >> 2;           // 0..1  (M half)
    const int wc = wid & 3;            // 0..3  (N quarter)
    const int l15 = lane & 15, lhi = lane >> 4;
    const int rsw = l15 & 7;

    int wg = blockIdx.y * gridDim.x + blockIdx.x;
    const int chunk = (gridDim.x * gridDim.y) >> 3;
    wg = (wg & 7) * chunk + (wg >> 3);
    const int bx = wg % gridDim.x, by = wg / gridDim.x;
    const int row0 = by * 256, col0 = bx * 256;

    const int kb = SPLIT ? blockIdx.z * K : 0;

    const int srow = tid >> 3;                         // 0..63
    const int scol = (((tid & 7) ^ (srow & 7)) << 3);  // pre-swizzled k-offset

    const int NT = K >> 6;

    f32x4 acc[8][4] = {};

    auto stageA = [&](int b, int h, int k0) {
#pragma unroll
        for (int j = 0; j < 2; ++j)
            gld16(&A[(size_t)(row0 + h * 128 + j * 64 + srow) * lda + kb + k0 + scol],
                  &Ab[b][h][j * 4096 + wid * 512]);
    };
    auto stageB = [&](int b, int h, int k0) {
#pragma unroll
        for (int j = 0; j < 2; ++j)
            gld16(&Bt[(size_t)(col0 + h * 128 + j * 64 + srow) * lda + kb + k0 + scol],
                  &Bb[b][h][j * 4096 + wid * 512]);
    };

    stageA(0, 0, 0); stageA(0, 1, 0);
    stageB(0, 0, 0); stageB(0, 1, 0);
    if (NT > 1) {
        stageB(1, 0, 64); stageB(1, 1, 64);
        asm volatile("s_waitcnt vmcnt(4)" ::: "memory");
    } else {
        asm volatile("s_waitcnt vmcnt(0)" ::: "memory");
    }
    __builtin_amdgcn_s_barrier();   // publication of t0

    short8 bfr[4][2], afA[2][2], afB[2][2];

    auto ldbfr = [&](int buf) {
#pragma unroll
        for (int n = 0; n < 4; ++n)
#pragma unroll
            for (int ks = 0; ks < 2; ++ks)
                bfr[n][ks] = *(const short8*)&Bb[buf][wc >> 1]
                    [((wc & 1) * 64 + n * 16 + l15) * 64 +
                     (((ks << 2) + lhi) ^ rsw) * 8];
    };
    auto ldaf = [&](short8 dst[2][2], int buf, int p) {
#pragma unroll
        for (int mi = 0; mi < 2; ++mi)
#pragma unroll
            for (int ks = 0; ks < 2; ++ks)
                dst[mi][ks] = *(const short8*)&Ab[buf][wr]
                    [((p * 2 + mi) * 16 + l15) * 64 +
                     (((ks << 2) + lhi) ^ rsw) * 8];
    };
    auto domfma = [&](short8 src[2][2], int p) {
        __builtin_amdgcn_s_setprio(1);
#pragma unroll
        for (int mi = 0; mi < 2; ++mi)
#pragma unroll
            for (int n = 0; n < 4; ++n)
#pragma unroll
                for (int ks = 0; ks < 2; ++ks)
                    acc[p * 2 + mi][n] = __builtin_amdgcn_mfma_f32_16x16x32_bf16(
                        src[mi][ks], bfr[n][ks], acc[p * 2 + mi][n], 0, 0, 0);
        __builtin_amdgcn_s_setprio(0);
    };

    for (int u = 0; u < NT; ++u) {
        const int buf = u & 1;
        // p0: reads for p0 issued pre-barrier (buf published at prev closing barrier)
        ldbfr(buf);
        ldaf(afA, buf, 0);
        if (u + 1 < NT) stageA(buf ^ 1, 0, (u + 1) << 6);
        __builtin_amdgcn_s_barrier();              // entry p0
        ldaf(afB, buf, 1);                         // pipelined: p1 reads under p0 MFMA
        domfma(afA, 0);
        __builtin_amdgcn_s_barrier();              // closing p0
        // p1
        if (u + 1 < NT) stageA(buf ^ 1, 1, (u + 1) << 6);
        __builtin_amdgcn_s_barrier();              // entry p1
        ldaf(afA, buf, 2);
        domfma(afB, 1);
        __builtin_amdgcn_s_barrier();              // closing p1
        // p2
        if (u + 2 < NT) stageB(buf, 0, (u + 2) << 6);
        __builtin_amdgcn_s_barrier();              // entry p2
        ldaf(afB, buf, 3);
        domfma(afA, 2);
        __builtin_amdgcn_s_barrier();              // closing p2
        // p3
        if (u + 2 < NT) stageB(buf, 1, (u + 2) << 6);
        __builtin_amdgcn_s_barrier();              // entry p3
        domfma(afB, 3);
        if (u + 1 < NT) {
            if (u + 2 < NT) asm volatile("s_waitcnt vmcnt(4)" ::: "memory");
            else            asm volatile("s_waitcnt vmcnt(0)" ::: "memory");
        }
        __builtin_amdgcn_s_barrier();              // closing p3 / publication
    }

    short* outb = (short*)outp;
    if (SPLIT) outb += (size_t)blockIdx.z * M * N;
#pragma unroll
    for (int m = 0; m < 8; ++m)
#pragma unroll
        for (int n = 0; n < 4; ++n)
#pragma unroll
            for (int r = 0; r < 4; ++r) {
                int row = row0 + wr * 128 + m * 16 + lhi * 4 + r;
                int col = col0 + wc * 64 + n * 16 + l15;
                float v = acc[m][n][r];
                if (!SPLIT) {
                    if (HAS_BIAS) v += bias[col];
                    if (RELU) v = fmaxf(v, 0.f);
                }
                outb[(size_t)row * N + col] = f2bf(v);
            }
}

// ---------------- bf16 GEMM 128xBN: 2-deep counted-vmcnt pipeline ----------------
template <int BN, int PIPE, bool HAS_BIAS, bool RELU, bool RESID, bool OUT_BF16>
__global__ __launch_bounds__(256) void gemm_bt(const short* __restrict__ A,
                                               const short* __restrict__ Bt,
                                               const float* __restrict__ bias,
                                               const float* __restrict__ resid,
                                               void* __restrict__ outp,
                                               int M, int N, int K) {
    constexpr int WRC = (BN == 128) ? 2 : 4;
    constexpr int WCC = (BN == 128) ? 2 : 1;
    constexpr int MI = 8 / WRC;
    constexpr int NI = BN / (16 * WCC);
    constexpr int BCH = BN / 32;
    constexpr int ASZ = 128 * 64, BSZ = BN * 64;

    __shared__ __align__(16) short As[(PIPE ? 2 : 1) * ASZ];
    __shared__ __align__(16) short Bs[(PIPE ? 2 : 1) * BSZ];

    const int tid = threadIdx.x;
    const int lane = tid & 63;
    const int wid = tid >> 6;
    const int wr = (WRC == 2) ? (wid >> 1) : wid;
    const int wc = (WCC == 2) ? (wid & 1) : 0;
    const int l15 = lane & 15, lhi = lane >> 4;

    int wg = blockIdx.y * gridDim.x + blockIdx.x;
    const int chunk = (gridDim.x * gridDim.y) >> 3;
    wg = (wg & 7) * chunk + (wg >> 3);
    const int bx = wg % gridDim.x;
    const int by = wg / gridDim.x;
    const int row0 = by * 128, col0 = bx * BN;

    const int srow = tid >> 3;
    const int scol = (((tid & 7) ^ (srow & 7)) << 3);
    const int rsw = l15 & 7;

    const int wrow0 = wr * (16 * MI);
    const int wcol0 = wc * (16 * NI);

    f32x4 acc[MI][NI] = {};

    auto stage = [&](int k0, int bs) {
#pragma unroll
        for (int ch = 0; ch < 4; ++ch)
            gld16(&A[(size_t)(row0 + ch * 32 + srow) * K + k0 + scol],
                  &As[bs * ASZ + ch * 2048 + wid * 512]);
#pragma unroll
        for (int ch = 0; ch < BCH; ++ch)
            gld16(&Bt[(size_t)(col0 + ch * 32 + srow) * K + k0 + scol],
                  &Bs[bs * BSZ + ch * 2048 + wid * 512]);
    };
    auto compute = [&](int bs) {
#pragma unroll
        for (int ks = 0; ks < 2; ++ks) {
            short8 af[MI], bf[NI];
#pragma unroll
            for (int mi = 0; mi < MI; ++mi)
                af[mi] = *(const short8*)&As[bs * ASZ + (wrow0 + mi * 16 + l15) * 64 +
                                             (((ks << 2) + lhi) ^ rsw) * 8];
#pragma unroll
            for (int ni = 0; ni < NI; ++ni)
                bf[ni] = *(const short8*)&Bs[bs * BSZ + (wcol0 + ni * 16 + l15) * 64 +
                                             (((ks << 2) + lhi) ^ rsw) * 8];
#pragma unroll
            for (int mi = 0; mi < MI; ++mi)
#pragma unroll
                for (int ni = 0; ni < NI; ++ni)
                    acc[mi][ni] = __builtin_amdgcn_mfma_f32_16x16x32_bf16(
                        af[mi], bf[ni], acc[mi][ni], 0, 0, 0);
        }
    };

    if (PIPE == 1) {
        const int nt = K >> 6;
        stage(0, 0);
        stage(64, 1);
        int cur = 0;
        for (int t = 0; t < nt; ++t) {
            if (t + 1 < nt) asm volatile("s_waitcnt vmcnt(6)" ::: "memory");
            else            asm volatile("s_waitcnt vmcnt(0)" ::: "memory");
            __builtin_amdgcn_s_barrier();
            __builtin_amdgcn_sched_barrier(0);
            compute(cur);
            __builtin_amdgcn_sched_barrier(0);
            __builtin_amdgcn_s_barrier();
            if (t + 2 < nt) stage((t + 2) << 6, cur);
            cur ^= 1;
        }
    } else {
        for (int k0 = 0; k0 < K; k0 += 64) {
            __syncthreads();
            stage(k0, 0);
            __syncthreads();
            compute(0);
        }
    }

    float* outf = (float*)outp;
    short* outb = (short*)outp;
#pragma unroll
    for (int mi = 0; mi < MI; ++mi)
#pragma unroll
        for (int ni = 0; ni < NI; ++ni)
#pragma unroll
            for (int r = 0; r < 4; ++r) {
                int row = row0 + wrow0 + mi * 16 + lhi * 4 + r;
                int col = col0 + wcol0 + ni * 16 + l15;
                float v = acc[mi][ni][r];
                if (HAS_BIAS) v += bias[col];
                if (RELU) v = fmaxf(v, 0.f);
                if (RESID) v += resid[(size_t)row * N + col];
                if (OUT_BF16) outb[(size_t)row * N + col] = f2bf(v);
                else outf[(size_t)row * N + col] = v;
            }
}

// ---------------- flash attention: 8 waves, QBLK=256, KVBLK=128, no-max softmax ----------------
__global__ __launch_bounds__(512) void attn_kernel(const short* __restrict__ qkv,
                                                   const short* __restrict__ vT,
                                                   short* __restrict__ obuf) {
    __shared__ __align__(16) short Ks[2][128 * 64];
    __shared__ __align__(16) short Vs[2][64 * 128];
    __shared__ __align__(16) unsigned int Pl[8][2][16][44];
    const int tid = threadIdx.x;
    const int lane = tid & 63;
    const int wid = tid >> 6;          // 0..7
    const int l15 = lane & 15, lhi = lane >> 4;
    const int lhi4 = lhi * 4;

    const int nb = ((blockIdx.x & 7) << 5) + (blockIdx.x >> 3);
    const int b = nb >> 6;
    const int h = (nb >> 2) & 15;
    const int q0 = (nb & 3) << 8;      // *256
    const size_t rbase = (size_t)b * TT;
    const int hq = h * 64;
    const short* vg = vT + ((size_t)b * 1024 + hq) * TT;

    const int srow = tid >> 3;                           // 0..63  (K stage row)
    const int scol = (((tid & 7) ^ (srow & 7)) << 3);
    const int vrow = tid >> 4;                           // 0..31  (V stage row)
    const int vscol = ((tid & 15) ^ (vrow & 7)) << 3;
    const int rsw = l15 & 7;

    short8 aq[2][2];
#pragma unroll
    for (int g = 0; g < 2; ++g)
#pragma unroll
        for (int ks = 0; ks < 2; ++ks)
            aq[g][ks] = *(const short8*)&qkv[(rbase + q0 + wid * 32 + g * 16 + l15) * NQKV +
                                             hq + ks * 32 + lhi * 8];

    f32x4 psum[2] = {};
    f32x4 o[2][4] = {};

    auto stage = [&](int buf, int st) {
#pragma unroll
        for (int ch = 0; ch < 2; ++ch)
            gld16(&qkv[(rbase + st + ch * 64 + srow) * NQKV + 1024 + hq + scol],
                  &Ks[buf][ch * 4096 + wid * 512]);
#pragma unroll
        for (int ch = 0; ch < 2; ++ch)
            gld16(&vg[(size_t)(ch * 32 + vrow) * TT + st + vscol],
                  &Vs[buf][ch * 4096 + wid * 512]);
    };

    stage(0, 0);
    __syncthreads();

    int cur = 0;
    for (int st = 0; st < TT; st += 128) {
        if (st + 128 < TT) stage(cur ^ 1, st + 128);
        const short* K = &Ks[cur][0];
        const short* V = &Vs[cur][0];

#pragma unroll
        for (int h2 = 0; h2 < 2; ++h2) {
            short8 kf[4][2];
#pragma unroll
            for (int nt = 0; nt < 4; ++nt)
#pragma unroll
                for (int ks = 0; ks < 2; ++ks)
                    kf[nt][ks] = *(const short8*)&K[(h2 * 64 + nt * 16 + l15) * 64 +
                                                   (((ks << 2) + lhi) ^ rsw) * 8];

            // QK^T for BOTH q-groups as one 16-MFMA cluster
            f32x4 stv[2][4] = {};
            __builtin_amdgcn_s_setprio(1);
#pragma unroll
            for (int g = 0; g < 2; ++g)
#pragma unroll
                for (int nt = 0; nt < 4; ++nt)
#pragma unroll
                    for (int ks = 0; ks < 2; ++ks)
                        stv[g][nt] = __builtin_amdgcn_mfma_f32_16x16x32_bf16(
                            kf[nt][ks], aq[g][ks], stv[g][nt], 0, 0, 0);
            __builtin_amdgcn_s_setprio(0);

            // no-max softmax for BOTH groups (one VALU cluster)
            short8 pa[2][2];
#pragma unroll
            for (int g = 0; g < 2; ++g) {
#pragma unroll
                for (int nt = 0; nt < 4; ++nt) {
                    f32x4 pv;
#pragma unroll
                    for (int r = 0; r < 4; ++r) pv[r] = exp2f(stv[g][nt][r]);
                    psum[g] += pv;
                    uint2 ww;
                    ww.x = cvtpk_bf16(pv[0], pv[1]);
                    ww.y = cvtpk_bf16(pv[2], pv[3]);
                    *(uint2*)&Pl[wid][g][l15][nt * 8 + lhi * 2] = ww;
                }
                pa[g][0] = *(const short8*)&Pl[wid][g][l15][lhi4];
                pa[g][1] = *(const short8*)&Pl[wid][g][l15][16 + lhi4];
            }

            short8 vf[4][2];
#pragma unroll
            for (int dt = 0; dt < 4; ++dt)
#pragma unroll
                for (int k2 = 0; k2 < 2; ++k2)
                    vf[dt][k2] = *(const short8*)&V[(dt * 16 + l15) * 128 +
                                                   ((h2 << 3) + (((k2 << 2) + lhi) ^ rsw)) * 8];
            __builtin_amdgcn_s_setprio(1);
#pragma unroll
            for (int g = 0; g < 2; ++g)
#pragma unroll
                for (int dt = 0; dt < 4; ++dt)
#pragma unroll
                    for (int k2 = 0; k2 < 2; ++k2)
                        o[g][dt] = __builtin_amdgcn_mfma_f32_16x16x32_bf16(
                            pa[g][k2], vf[dt][k2], o[g][dt], 0, 0, 0);
            __builtin_amdgcn_s_setprio(0);
        }

        __syncthreads();
        cur ^= 1;
    }
#pragma unroll
    for (int g = 0; g < 2; ++g) {
        float ls = (psum[g][0] + psum[g][1]) + (psum[g][2] + psum[g][3]);
        ls += __shfl_xor(ls, 16, 64);
        ls += __shfl_xor(ls, 32, 64);
        float inv = 1.0f / ls;
        float i0 = __shfl(inv, lhi4 + 0, 64);
        float i1 = __shfl(inv, lhi4 + 1, 64);
        float i2 = __shfl(inv, lhi4 + 2, 64);
        float i3 = __shfl(inv, lhi4 + 3, 64);
#pragma unroll
        for (int dt = 0; dt < 4; ++dt) {
            int col = hq + dt * 16 + l15;
            size_t rw = rbase + q0 + wid * 32 + g * 16 + lhi4;
            obuf[(rw + 0) * EE + col] = f2bf(o[g][dt][0] * i0);
            obuf[(rw + 1) * EE + col] = f2bf(o[g][dt][1] * i1);
            obuf[(rw + 2) * EE + col] = f2bf(o[g][dt][2] * i2);
            obuf[(rw + 3) * EE + col] = f2bf(o[g][dt][3] * i3);
        }
    }
}

// ---------------- launch ----------------
extern "C" void kernel_launch(void* const* d_in, const int* in_sizes, int n_in,
                              void* d_out, int out_size, void* d_ws, size_t ws_size,
                              hipStream_t stream) {
    const float* x   = (const float*)d_in[0];
    const float* g1  = (const float*)d_in[1];
    const float* be1 = (const float*)d_in[2];
    const float* Wq  = (const float*)d_in[3];
    const float* Wk  = (const float*)d_in[4];
    const float* Wv  = (const float*)d_in[5];
    const float* Wp  = (const float*)d_in[6];
    const float* bp  = (const float*)d_in[7];
    const float* g2  = (const float*)d_in[8];
    const float* be2 = (const float*)d_in[9];
    const float* W1  = (const float*)d_in[10];
    const float* b1f = (const float*)d_in[11];
    const float* W2  = (const float*)d_in[12];
    const float* b2f = (const float*)d_in[13];

    char* p = (char*)d_ws;
    short* h_bf   = (short*)p; p += (size_t)MM * EE * 2;          // [0,8M)
    short* wqkv   = (short*)p; p += (size_t)EE * NQKV * 2;        // [8M,14M)
    short* qkv    = (short*)p; p += (size_t)MM * NQKV * 2;        // [14M,38M)
    short* o_bf   = (short*)p; p += (size_t)MM * EE * 2;          // [38M,46M)
    short* wp_bf  = (short*)p; p += (size_t)EE * EE * 2;          // [46M,48M)
    float* x1     = (float*)p; p += (size_t)MM * EE * 4;          // [48M,64M) LIVE
    short* h2_bf  = (short*)p; p += (size_t)MM * EE * 2;          // [64M,72M)
    short* w1_bf  = (short*)p; p += (size_t)EE * E4 * 2;          // [72M,80M)
    short* mid_bf = (short*)p; p += (size_t)MM * E4 * 2;
    short* w2_bf  = (short*)p; p += (size_t)E4 * EE * 2;
    short* vTb    = (short*)p; p += (size_t)BB * 1024 * TT * 2;   // [b][h*64+d][t]

    // FFN2 split-K=4 bf16 partials: 4 x 8 MB contiguous in ws[0..32M)
    short* parts = (short*)d_ws;

    packs_kernel<<<3072, 256, 0, stream>>>(Wq, Wk, Wv, Wp, W1, W2,
                                           wqkv, wp_bf, w1_bf, w2_bf);

    ln_kernel<<<MM, 256, 0, stream>>>(x, g1, be1, h_bf);

    gemm256<false, false, false>
        <<<dim3(NQKV / 256, MM / 256), 512, 0, stream>>>(h_bf, wqkv, nullptr,
                                                         qkv, MM, NQKV, EE, EE);

    vtr_kernel<<<dim3(16, 16, BB), 256, 0, stream>>>(qkv, vTb);

    attn_kernel<<<BB * HH * (TT / 256), 512, 0, stream>>>(qkv, vTb, o_bf);

    gemm_bt<64, 1, true, false, true, false>
        <<<dim3(EE / 64, MM / 128), 256, 0, stream>>>(o_bf, wp_bf, bp, x, x1, MM, EE, EE);

    ln_kernel<<<MM, 256, 0, stream>>>(x1, g2, be2, h2_bf);

    gemm256<true, true, false>
        <<<dim3(E4 / 256, MM / 256), 512, 0, stream>>>(h2_bf, w1_bf, b1f,
                                                       mid_bf, MM, E4, EE, EE);

    // FFN2: 256^2-tile split-K=4, bf16 partials, then fused reduce
    gemm256<false, false, true>
        <<<dim3(EE / 256, MM / 256, 4), 512, 0, stream>>>(mid_bf, w2_bf, nullptr,
                                                          parts, MM, EE, 1024, E4);
    redk4_kernel<<<(MM * EE / 8) / 256, 256, 0, stream>>>(parts, b2f, x1,
                                                          (float*)d_out);
}

// Round 21
// 198.314 us; speedup vs baseline: 1.0995x; 1.0995x over previous
//
#include <hip/hip_runtime.h>
#include <hip/hip_bf16.h>

// Problem constants (B,T,E,H,D) = (4,1024,1024,16,64)
#define BB 4
#define TT 1024
#define EE 1024
#define HH 16
#define DD 64
#define MM 4096    // B*T rows
#define NQKV 3072  // q|k|v packed cols
#define E4 4096    // 4*E

using short8  = __attribute__((ext_vector_type(8))) short;
using short4v = __attribute__((ext_vector_type(4))) short;
using f32x4   = __attribute__((ext_vector_type(4))) float;

__device__ __forceinline__ short f2bf(float f) {
    __hip_bfloat16 h = __float2bfloat16(f);
    return *reinterpret_cast<short*>(&h);
}

__device__ __forceinline__ float bf2f(short s) {
    unsigned int u = ((unsigned int)(unsigned short)s) << 16;
    return __uint_as_float(u);
}

// pack two f32 -> one u32 of 2 bf16 (low = a, high = b); no builtin on gfx950
__device__ __forceinline__ unsigned int cvtpk_bf16(float a, float b) {
    unsigned int w;
    asm("v_cvt_pk_bf16_f32 %0, %1, %2" : "=v"(w) : "v"(a), "v"(b));
    return w;
}

// async global->LDS, 16B per lane. LDS dest is wave-uniform base + lane*16.
__device__ __forceinline__ void gld16(const void* g, void* l) {
    __builtin_amdgcn_global_load_lds((__attribute__((address_space(1))) void*)g,
                                     (__attribute__((address_space(3))) void*)l,
                                     16, 0, 0);
}

// ---------------- fused weight packs (one launch, float4 loads) ----------------
__device__ __forceinline__ void tcvt_tile(const float* __restrict__ in,
                                          short* __restrict__ out,
                                          int R, int C, int r0, int c0,
                                          float scale) {
    __shared__ short tile[64][68];
    const int rr = threadIdx.x >> 4;          // 0..15
    const int c4 = (threadIdx.x & 15) * 4;    // 0..60
#pragma unroll
    for (int i = 0; i < 4; ++i) {
        int r = i * 16 + rr;
        float4 v = *(const float4*)&in[(size_t)(r0 + r) * C + c0 + c4];
        tile[c4 + 0][r] = f2bf(v.x * scale);
        tile[c4 + 1][r] = f2bf(v.y * scale);
        tile[c4 + 2][r] = f2bf(v.z * scale);
        tile[c4 + 3][r] = f2bf(v.w * scale);
    }
    __syncthreads();
#pragma unroll
    for (int i = 0; i < 4; ++i) {
        int c = i * 16 + rr;
        short4v s = *(const short4v*)&tile[c][c4];
        *(short4v*)&out[(size_t)(c0 + c) * R + r0 + c4] = s;
    }
}

__global__ __launch_bounds__(256) void packs_kernel(const float* __restrict__ Wq,
                                                    const float* __restrict__ Wk,
                                                    const float* __restrict__ Wv,
                                                    const float* __restrict__ Wp,
                                                    const float* __restrict__ W1,
                                                    const float* __restrict__ W2,
                                                    short* __restrict__ wqkv,
                                                    short* __restrict__ wp_bf,
                                                    short* __restrict__ w1_bf,
                                                    short* __restrict__ w2_bf) {
    const int blk = blockIdx.x;
    if (blk < 768) {
        const int m = blk >> 4;            // 0..47
        const int which = m >> 4, head = m & 15;
        const float* src = ((which == 0) ? Wq : (which == 1) ? Wk : Wv) +
                           (size_t)head * EE * DD;
        const float scale = (which == 1) ? 1.44269504f : 1.0f;
        const int e0 = (blk & 15) * 64;
        tcvt_tile(src, wqkv + (size_t)(which * 1024 + head * 64) * EE,
                  EE, DD, e0, 0, scale);
    } else if (blk < 1024) {
        const int idx = blk - 768;
        tcvt_tile(Wp, wp_bf, EE, EE, (idx >> 4) * 64, (idx & 15) * 64, 1.0f);
    } else if (blk < 2048) {
        const int idx = blk - 1024;
        tcvt_tile(W1, w1_bf, EE, E4, (idx >> 6) * 64, (idx & 63) * 64, 1.0f);
    } else {
        const int idx = blk - 2048;
        tcvt_tile(W2, w2_bf, E4, EE, (idx >> 4) * 64, (idx & 15) * 64, 1.0f);
    }
}

// ---------------- V transpose: qkv V-part [b*T+t][2048 + c] -> vT[(b*1024+c)][t] ----------------
__global__ __launch_bounds__(256) void vtr_kernel(const short* __restrict__ qkv,
                                                  short* __restrict__ vT) {
    __shared__ short tile[64][68];
    const int b = blockIdx.z;
    const int t0 = blockIdx.x * 64, c0 = blockIdx.y * 64;
    const int tr = threadIdx.x >> 4;          // 0..15
    const int q4 = (threadIdx.x & 15) * 4;    // 0..60
#pragma unroll
    for (int i = 0; i < 4; ++i) {
        int t = i * 16 + tr;
        short4v v = *(const short4v*)&qkv[((size_t)b * TT + t0 + t) * NQKV + 2048 + c0 + q4];
        *(short4v*)&tile[t][q4] = v;
    }
    __syncthreads();
#pragma unroll
    for (int i = 0; i < 4; ++i) {
        int c = i * 16 + tr;
        short4v v;
        v[0] = tile[q4 + 0][c];
        v[1] = tile[q4 + 1][c];
        v[2] = tile[q4 + 2][c];
        v[3] = tile[q4 + 3][c];
        *(short4v*)&vT[((size_t)b * 1024 + c0 + c) * TT + t0 + q4] = v;
    }
}

// ---------------- LayerNorm (fp32 in -> bf16 out) ----------------
__global__ __launch_bounds__(256) void ln_kernel(const float* __restrict__ x,
                                                 const float* __restrict__ g,
                                                 const float* __restrict__ b,
                                                 short* __restrict__ out) {
    __shared__ float red[4];
    const int row = blockIdx.x;
    const int tid = threadIdx.x;
    float4 v = *(const float4*)&x[(size_t)row * EE + tid * 4];
    float s = v.x + v.y + v.z + v.w;
#pragma unroll
    for (int off = 32; off >= 1; off >>= 1) s += __shfl_xor(s, off, 64);
    if ((tid & 63) == 0) red[tid >> 6] = s;
    __syncthreads();
    float mean = (red[0] + red[1] + red[2] + red[3]) * (1.0f / EE);
    __syncthreads();
    float d0 = v.x - mean, d1 = v.y - mean, d2 = v.z - mean, d3 = v.w - mean;
    s = d0 * d0 + d1 * d1 + d2 * d2 + d3 * d3;
#pragma unroll
    for (int off = 32; off >= 1; off >>= 1) s += __shfl_xor(s, off, 64);
    if ((tid & 63) == 0) red[tid >> 6] = s;
    __syncthreads();
    float var = (red[0] + red[1] + red[2] + red[3]) * (1.0f / EE);
    float rstd = rsqrtf(var + 1e-5f);
    int c = tid * 4;
    short4v o;
    o[0] = f2bf(d0 * rstd * g[c + 0] + b[c + 0]);
    o[1] = f2bf(d1 * rstd * g[c + 1] + b[c + 1]);
    o[2] = f2bf(d2 * rstd * g[c + 2] + b[c + 2]);
    o[3] = f2bf(d3 * rstd * g[c + 3] + b[c + 3]);
    *(short4v*)&out[(size_t)row * EE + c] = o;
}

// ---------------- split-K=4 reduce (bf16 partials, 8 elem/thread) ----------------
__global__ __launch_bounds__(256) void redk4_kernel(const short* __restrict__ parts,
                                                    const float* __restrict__ bias,
                                                    const float* __restrict__ resid,
                                                    float* __restrict__ out) {
    const size_t i = ((size_t)blockIdx.x * 256 + threadIdx.x) * 8;
    float4 r0 = *(const float4*)&resid[i];
    float4 r1 = *(const float4*)&resid[i + 4];
    const float* bb = &bias[i & 1023];
    float4 b0 = *(const float4*)&bb[0];
    float4 b1 = *(const float4*)&bb[4];
    float acc[8];
    acc[0] = r0.x + b0.x; acc[1] = r0.y + b0.y;
    acc[2] = r0.z + b0.z; acc[3] = r0.w + b0.w;
    acc[4] = r1.x + b1.x; acc[5] = r1.y + b1.y;
    acc[6] = r1.z + b1.z; acc[7] = r1.w + b1.w;
#pragma unroll
    for (int z = 0; z < 4; ++z) {
        short8 p = *(const short8*)&parts[(size_t)z * MM * EE + i];
#pragma unroll
        for (int j = 0; j < 8; ++j) acc[j] += bf2f(p[j]);
    }
    float4 o0, o1;
    o0.x = acc[0]; o0.y = acc[1]; o0.z = acc[2]; o0.w = acc[3];
    o1.x = acc[4]; o1.y = acc[5]; o1.z = acc[6]; o1.w = acc[7];
    *(float4*)&out[i] = o0;
    *(float4*)&out[i + 4] = o1;
}

// ---------------- 256x256 8-phase bf16 GEMM (T2+T3+T4+T5) ----------------
// SPLIT: K is the per-z chunk length, lda the full row stride; bf16 partial
// out at outp + z*M*N, no bias/relu.
template <bool HAS_BIAS, bool RELU, bool SPLIT>
__global__ __launch_bounds__(512, 2) void gemm256(const short* __restrict__ A,
                                                  const short* __restrict__ Bt,
                                                  const float* __restrict__ bias,
                                                  void* __restrict__ outp,
                                                  int M, int N, int K, int lda) {
    __shared__ __align__(16) short Ab[2][2][8192];   // [buf][half][128*64]
    __shared__ __align__(16) short Bb[2][2][8192];

    const int tid = threadIdx.x;
    const int lane = tid & 63;
    const int wid = tid >> 6;          // 0..7
    const int wr = wid >> 2;           // 0..1  (M half)
    const int wc = wid & 3;            // 0..3  (N quarter)
    const int l15 = lane & 15, lhi = lane >> 4;
    const int rsw = l15 & 7;

    int wg = blockIdx.y * gridDim.x + blockIdx.x;
    const int chunk = (gridDim.x * gridDim.y) >> 3;
    wg = (wg & 7) * chunk + (wg >> 3);
    const int bx = wg % gridDim.x, by = wg / gridDim.x;
    const int row0 = by * 256, col0 = bx * 256;

    const int kb = SPLIT ? blockIdx.z * K : 0;

    const int srow = tid >> 3;                         // 0..63
    const int scol = (((tid & 7) ^ (srow & 7)) << 3);  // pre-swizzled k-offset

    const int NT = K >> 6;

    f32x4 acc[8][4] = {};

    auto stageA = [&](int b, int h, int k0) {
#pragma unroll
        for (int j = 0; j < 2; ++j)
            gld16(&A[(size_t)(row0 + h * 128 + j * 64 + srow) * lda + kb + k0 + scol],
                  &Ab[b][h][j * 4096 + wid * 512]);
    };
    auto stageB = [&](int b, int h, int k0) {
#pragma unroll
        for (int j = 0; j < 2; ++j)
            gld16(&Bt[(size_t)(col0 + h * 128 + j * 64 + srow) * lda + kb + k0 + scol],
                  &Bb[b][h][j * 4096 + wid * 512]);
    };

    stageA(0, 0, 0); stageA(0, 1, 0);
    stageB(0, 0, 0); stageB(0, 1, 0);
    if (NT > 1) {
        stageB(1, 0, 64); stageB(1, 1, 64);
        asm volatile("s_waitcnt vmcnt(4)" ::: "memory");
    } else {
        asm volatile("s_waitcnt vmcnt(0)" ::: "memory");
    }
    __builtin_amdgcn_s_barrier();   // publication of t0

    for (int u = 0; u < NT; ++u) {
        const int buf = u & 1;
        short8 bfr[4][2];
#pragma unroll
        for (int p = 0; p < 4; ++p) {
            if (p == 0) {
#pragma unroll
                for (int n = 0; n < 4; ++n)
#pragma unroll
                    for (int ks = 0; ks < 2; ++ks)
                        bfr[n][ks] = *(const short8*)&Bb[buf][wc >> 1]
                            [((wc & 1) * 64 + n * 16 + l15) * 64 +
                             (((ks << 2) + lhi) ^ rsw) * 8];
            }
            short8 af[2][2];
#pragma unroll
            for (int mi = 0; mi < 2; ++mi)
#pragma unroll
                for (int ks = 0; ks < 2; ++ks)
                    af[mi][ks] = *(const short8*)&Ab[buf][wr]
                        [((p * 2 + mi) * 16 + l15) * 64 +
                         (((ks << 2) + lhi) ^ rsw) * 8];
            if (p == 0 && u + 1 < NT) stageA(buf ^ 1, 0, (u + 1) << 6);
            if (p == 1 && u + 1 < NT) stageA(buf ^ 1, 1, (u + 1) << 6);
            if (p == 2 && u + 2 < NT) stageB(buf, 0, (u + 2) << 6);
            if (p == 3 && u + 2 < NT) stageB(buf, 1, (u + 2) << 6);
            __builtin_amdgcn_s_barrier();          // entry
            __builtin_amdgcn_s_setprio(1);
#pragma unroll
            for (int mi = 0; mi < 2; ++mi)
#pragma unroll
                for (int n = 0; n < 4; ++n)
#pragma unroll
                    for (int ks = 0; ks < 2; ++ks)
                        acc[p * 2 + mi][n] = __builtin_amdgcn_mfma_f32_16x16x32_bf16(
                            af[mi][ks], bfr[n][ks], acc[p * 2 + mi][n], 0, 0, 0);
            __builtin_amdgcn_s_setprio(0);
            if (p == 3 && u + 1 < NT) {
                if (u + 2 < NT) asm volatile("s_waitcnt vmcnt(4)" ::: "memory");
                else            asm volatile("s_waitcnt vmcnt(0)" ::: "memory");
            }
            __builtin_amdgcn_s_barrier();          // closing / publication
        }
    }

    short* outb = (short*)outp;
    if (SPLIT) outb += (size_t)blockIdx.z * M * N;
#pragma unroll
    for (int m = 0; m < 8; ++m)
#pragma unroll
        for (int n = 0; n < 4; ++n)
#pragma unroll
            for (int r = 0; r < 4; ++r) {
                int row = row0 + wr * 128 + m * 16 + lhi * 4 + r;
                int col = col0 + wc * 64 + n * 16 + l15;
                float v = acc[m][n][r];
                if (!SPLIT) {
                    if (HAS_BIAS) v += bias[col];
                    if (RELU) v = fmaxf(v, 0.f);
                }
                outb[(size_t)row * N + col] = f2bf(v);
            }
}

// ---------------- bf16 GEMM 128xBN: 2-deep counted-vmcnt pipeline ----------------
template <int BN, int PIPE, bool HAS_BIAS, bool RELU, bool RESID, bool OUT_BF16>
__global__ __launch_bounds__(256) void gemm_bt(const short* __restrict__ A,
                                               const short* __restrict__ Bt,
                                               const float* __restrict__ bias,
                                               const float* __restrict__ resid,
                                               void* __restrict__ outp,
                                               int M, int N, int K) {
    constexpr int WRC = (BN == 128) ? 2 : 4;
    constexpr int WCC = (BN == 128) ? 2 : 1;
    constexpr int MI = 8 / WRC;
    constexpr int NI = BN / (16 * WCC);
    constexpr int BCH = BN / 32;
    constexpr int ASZ = 128 * 64, BSZ = BN * 64;

    __shared__ __align__(16) short As[(PIPE ? 2 : 1) * ASZ];
    __shared__ __align__(16) short Bs[(PIPE ? 2 : 1) * BSZ];

    const int tid = threadIdx.x;
    const int lane = tid & 63;
    const int wid = tid >> 6;
    const int wr = (WRC == 2) ? (wid >> 1) : wid;
    const int wc = (WCC == 2) ? (wid & 1) : 0;
    const int l15 = lane & 15, lhi = lane >> 4;

    int wg = blockIdx.y * gridDim.x + blockIdx.x;
    const int chunk = (gridDim.x * gridDim.y) >> 3;
    wg = (wg & 7) * chunk + (wg >> 3);
    const int bx = wg % gridDim.x;
    const int by = wg / gridDim.x;
    const int row0 = by * 128, col0 = bx * BN;

    const int srow = tid >> 3;
    const int scol = (((tid & 7) ^ (srow & 7)) << 3);
    const int rsw = l15 & 7;

    const int wrow0 = wr * (16 * MI);
    const int wcol0 = wc * (16 * NI);

    f32x4 acc[MI][NI] = {};

    auto stage = [&](int k0, int bs) {
#pragma unroll
        for (int ch = 0; ch < 4; ++ch)
            gld16(&A[(size_t)(row0 + ch * 32 + srow) * K + k0 + scol],
                  &As[bs * ASZ + ch * 2048 + wid * 512]);
#pragma unroll
        for (int ch = 0; ch < BCH; ++ch)
            gld16(&Bt[(size_t)(col0 + ch * 32 + srow) * K + k0 + scol],
                  &Bs[bs * BSZ + ch * 2048 + wid * 512]);
    };
    auto compute = [&](int bs) {
#pragma unroll
        for (int ks = 0; ks < 2; ++ks) {
            short8 af[MI], bf[NI];
#pragma unroll
            for (int mi = 0; mi < MI; ++mi)
                af[mi] = *(const short8*)&As[bs * ASZ + (wrow0 + mi * 16 + l15) * 64 +
                                             (((ks << 2) + lhi) ^ rsw) * 8];
#pragma unroll
            for (int ni = 0; ni < NI; ++ni)
                bf[ni] = *(const short8*)&Bs[bs * BSZ + (wcol0 + ni * 16 + l15) * 64 +
                                             (((ks << 2) + lhi) ^ rsw) * 8];
#pragma unroll
            for (int mi = 0; mi < MI; ++mi)
#pragma unroll
                for (int ni = 0; ni < NI; ++ni)
                    acc[mi][ni] = __builtin_amdgcn_mfma_f32_16x16x32_bf16(
                        af[mi], bf[ni], acc[mi][ni], 0, 0, 0);
        }
    };

    if (PIPE == 1) {
        const int nt = K >> 6;
        stage(0, 0);
        stage(64, 1);
        int cur = 0;
        for (int t = 0; t < nt; ++t) {
            if (t + 1 < nt) asm volatile("s_waitcnt vmcnt(6)" ::: "memory");
            else            asm volatile("s_waitcnt vmcnt(0)" ::: "memory");
            __builtin_amdgcn_s_barrier();
            __builtin_amdgcn_sched_barrier(0);
            compute(cur);
            __builtin_amdgcn_sched_barrier(0);
            __builtin_amdgcn_s_barrier();
            if (t + 2 < nt) stage((t + 2) << 6, cur);
            cur ^= 1;
        }
    } else {
        for (int k0 = 0; k0 < K; k0 += 64) {
            __syncthreads();
            stage(k0, 0);
            __syncthreads();
            compute(0);
        }
    }

    float* outf = (float*)outp;
    short* outb = (short*)outp;
#pragma unroll
    for (int mi = 0; mi < MI; ++mi)
#pragma unroll
        for (int ni = 0; ni < NI; ++ni)
#pragma unroll
            for (int r = 0; r < 4; ++r) {
                int row = row0 + wrow0 + mi * 16 + lhi * 4 + r;
                int col = col0 + wcol0 + ni * 16 + l15;
                float v = acc[mi][ni][r];
                if (HAS_BIAS) v += bias[col];
                if (RELU) v = fmaxf(v, 0.f);
                if (RESID) v += resid[(size_t)row * N + col];
                if (OUT_BF16) outb[(size_t)row * N + col] = f2bf(v);
                else outf[(size_t)row * N + col] = v;
            }
}

// ---------------- flash attention: 8 waves, QBLK=256, KVBLK=128, no-max softmax ----------------
// Batched clusters per half: 16-MFMA QK (both q-groups), then one VALU softmax
// cluster (both groups), then 16-MFMA PV. Pl has a per-group copy.
__global__ __launch_bounds__(512) void attn_kernel(const short* __restrict__ qkv,
                                                   const short* __restrict__ vT,
                                                   short* __restrict__ obuf) {
    __shared__ __align__(16) short Ks[2][128 * 64];
    __shared__ __align__(16) short Vs[2][64 * 128];
    __shared__ __align__(16) unsigned int Pl[8][2][16][44];
    const int tid = threadIdx.x;
    const int lane = tid & 63;
    const int wid = tid >> 6;          // 0..7
    const int l15 = lane & 15, lhi = lane >> 4;
    const int lhi4 = lhi * 4;

    const int nb = ((blockIdx.x & 7) << 5) + (blockIdx.x >> 3);
    const int b = nb >> 6;
    const int h = (nb >> 2) & 15;
    const int q0 = (nb & 3) << 8;      // *256
    const size_t rbase = (size_t)b * TT;
    const int hq = h * 64;
    const short* vg = vT + ((size_t)b * 1024 + hq) * TT;

    const int srow = tid >> 3;                           // 0..63  (K stage row)
    const int scol = (((tid & 7) ^ (srow & 7)) << 3);
    const int vrow = tid >> 4;                           // 0..31  (V stage row)
    const int vscol = ((tid & 15) ^ (vrow & 7)) << 3;
    const int rsw = l15 & 7;

    short8 aq[2][2];
#pragma unroll
    for (int g = 0; g < 2; ++g)
#pragma unroll
        for (int ks = 0; ks < 2; ++ks)
            aq[g][ks] = *(const short8*)&qkv[(rbase + q0 + wid * 32 + g * 16 + l15) * NQKV +
                                             hq + ks * 32 + lhi * 8];

    f32x4 psum[2] = {};
    f32x4 o[2][4] = {};

    auto stage = [&](int buf, int st) {
#pragma unroll
        for (int ch = 0; ch < 2; ++ch)
            gld16(&qkv[(rbase + st + ch * 64 + srow) * NQKV + 1024 + hq + scol],
                  &Ks[buf][ch * 4096 + wid * 512]);
#pragma unroll
        for (int ch = 0; ch < 2; ++ch)
            gld16(&vg[(size_t)(ch * 32 + vrow) * TT + st + vscol],
                  &Vs[buf][ch * 4096 + wid * 512]);
    };

    stage(0, 0);
    __syncthreads();

    int cur = 0;
    for (int st = 0; st < TT; st += 128) {
        if (st + 128 < TT) stage(cur ^ 1, st + 128);
        const short* K = &Ks[cur][0];
        const short* V = &Vs[cur][0];

#pragma unroll
        for (int h2 = 0; h2 < 2; ++h2) {
            short8 kf[4][2];
#pragma unroll
            for (int nt = 0; nt < 4; ++nt)
#pragma unroll
                for (int ks = 0; ks < 2; ++ks)
                    kf[nt][ks] = *(const short8*)&K[(h2 * 64 + nt * 16 + l15) * 64 +
                                                   (((ks << 2) + lhi) ^ rsw) * 8];

            // QK^T for BOTH q-groups as one 16-MFMA cluster
            f32x4 stv[2][4] = {};
            __builtin_amdgcn_s_setprio(1);
#pragma unroll
            for (int g = 0; g < 2; ++g)
#pragma unroll
                for (int nt = 0; nt < 4; ++nt)
#pragma unroll
                    for (int ks = 0; ks < 2; ++ks)
                        stv[g][nt] = __builtin_amdgcn_mfma_f32_16x16x32_bf16(
                            kf[nt][ks], aq[g][ks], stv[g][nt], 0, 0, 0);
            __builtin_amdgcn_s_setprio(0);

            // no-max softmax for BOTH groups (one VALU cluster)
            short8 pa[2][2];
#pragma unroll
            for (int g = 0; g < 2; ++g) {
#pragma unroll
                for (int nt = 0; nt < 4; ++nt) {
                    f32x4 pv;
#pragma unroll
                    for (int r = 0; r < 4; ++r) pv[r] = exp2f(stv[g][nt][r]);
                    psum[g] += pv;
                    uint2 ww;
                    ww.x = cvtpk_bf16(pv[0], pv[1]);
                    ww.y = cvtpk_bf16(pv[2], pv[3]);
                    *(uint2*)&Pl[wid][g][l15][nt * 8 + lhi * 2] = ww;
                }
                pa[g][0] = *(const short8*)&Pl[wid][g][l15][lhi4];
                pa[g][1] = *(const short8*)&Pl[wid][g][l15][16 + lhi4];
            }

            short8 vf[4][2];
#pragma unroll
            for (int dt = 0; dt < 4; ++dt)
#pragma unroll
                for (int k2 = 0; k2 < 2; ++k2)
                    vf[dt][k2] = *(const short8*)&V[(dt * 16 + l15) * 128 +
                                                   ((h2 << 3) + (((k2 << 2) + lhi) ^ rsw)) * 8];
            __builtin_amdgcn_s_setprio(1);
#pragma unroll
            for (int g = 0; g < 2; ++g)
#pragma unroll
                for (int dt = 0; dt < 4; ++dt)
#pragma unroll
                    for (int k2 = 0; k2 < 2; ++k2)
                        o[g][dt] = __builtin_amdgcn_mfma_f32_16x16x32_bf16(
                            pa[g][k2], vf[dt][k2], o[g][dt], 0, 0, 0);
            __builtin_amdgcn_s_setprio(0);
        }

        __syncthreads();
        cur ^= 1;
    }
#pragma unroll
    for (int g = 0; g < 2; ++g) {
        float ls = (psum[g][0] + psum[g][1]) + (psum[g][2] + psum[g][3]);
        ls += __shfl_xor(ls, 16, 64);
        ls += __shfl_xor(ls, 32, 64);
        float inv = 1.0f / ls;
        float i0 = __shfl(inv, lhi4 + 0, 64);
        float i1 = __shfl(inv, lhi4 + 1, 64);
        float i2 = __shfl(inv, lhi4 + 2, 64);
        float i3 = __shfl(inv, lhi4 + 3, 64);
#pragma unroll
        for (int dt = 0; dt < 4; ++dt) {
            int col = hq + dt * 16 + l15;
            size_t rw = rbase + q0 + wid * 32 + g * 16 + lhi4;
            obuf[(rw + 0) * EE + col] = f2bf(o[g][dt][0] * i0);
            obuf[(rw + 1) * EE + col] = f2bf(o[g][dt][1] * i1);
            obuf[(rw + 2) * EE + col] = f2bf(o[g][dt][2] * i2);
            obuf[(rw + 3) * EE + col] = f2bf(o[g][dt][3] * i3);
        }
    }
}

// ---------------- launch ----------------
extern "C" void kernel_launch(void* const* d_in, const int* in_sizes, int n_in,
                              void* d_out, int out_size, void* d_ws, size_t ws_size,
                              hipStream_t stream) {
    const float* x   = (const float*)d_in[0];
    const float* g1  = (const float*)d_in[1];
    const float* be1 = (const float*)d_in[2];
    const float* Wq  = (const float*)d_in[3];
    const float* Wk  = (const float*)d_in[4];
    const float* Wv  = (const float*)d_in[5];
    const float* Wp  = (const float*)d_in[6];
    const float* bp  = (const float*)d_in[7];
    const float* g2  = (const float*)d_in[8];
    const float* be2 = (const float*)d_in[9];
    const float* W1  = (const float*)d_in[10];
    const float* b1f = (const float*)d_in[11];
    const float* W2  = (const float*)d_in[12];
    const float* b2f = (const float*)d_in[13];

    char* p = (char*)d_ws;
    short* h_bf   = (short*)p; p += (size_t)MM * EE * 2;          // [0,8M)
    short* wqkv   = (short*)p; p += (size_t)EE * NQKV * 2;        // [8M,14M)
    short* qkv    = (short*)p; p += (size_t)MM * NQKV * 2;        // [14M,38M)
    short* o_bf   = (short*)p; p += (size_t)MM * EE * 2;          // [38M,46M)
    short* wp_bf  = (short*)p; p += (size_t)EE * EE * 2;          // [46M,48M)
    float* x1     = (float*)p; p += (size_t)MM * EE * 4;          // [48M,64M) LIVE
    short* h2_bf  = (short*)p; p += (size_t)MM * EE * 2;          // [64M,72M)
    short* w1_bf  = (short*)p; p += (size_t)EE * E4 * 2;          // [72M,80M)
    short* mid_bf = (short*)p; p += (size_t)MM * E4 * 2;
    short* w2_bf  = (short*)p; p += (size_t)E4 * EE * 2;
    short* vTb    = (short*)p; p += (size_t)BB * 1024 * TT * 2;   // [b][h*64+d][t]

    // FFN2 split-K=4 bf16 partials: 4 x 8 MB contiguous in ws[0..32M)
    // (h_bf + wqkv + qkv head — all dead by FFN2; o_bf/x1 untouched).
    short* parts = (short*)d_ws;

    packs_kernel<<<3072, 256, 0, stream>>>(Wq, Wk, Wv, Wp, W1, W2,
                                           wqkv, wp_bf, w1_bf, w2_bf);

    ln_kernel<<<MM, 256, 0, stream>>>(x, g1, be1, h_bf);

    gemm256<false, false, false>
        <<<dim3(NQKV / 256, MM / 256), 512, 0, stream>>>(h_bf, wqkv, nullptr,
                                                         qkv, MM, NQKV, EE, EE);

    vtr_kernel<<<dim3(16, 16, BB), 256, 0, stream>>>(qkv, vTb);

    attn_kernel<<<BB * HH * (TT / 256), 512, 0, stream>>>(qkv, vTb, o_bf);

    gemm_bt<64, 1, true, false, true, false>
        <<<dim3(EE / 64, MM / 128), 256, 0, stream>>>(o_bf, wp_bf, bp, x, x1, MM, EE, EE);

    ln_kernel<<<MM, 256, 0, stream>>>(x1, g2, be2, h2_bf);

    gemm256<true, true, false>
        <<<dim3(E4 / 256, MM / 256), 512, 0, stream>>>(h2_bf, w1_bf, b1f,
                                                       mid_bf, MM, E4, EE, EE);

    // FFN2: 256^2-tile split-K=4, bf16 partials, then fused reduce
    gemm256<false, false, true>
        <<<dim3(EE / 256, MM / 256, 4), 512, 0, stream>>>(mid_bf, w2_bf, nullptr,
                                                          parts, MM, EE, 1024, E4);
    redk4_kernel<<<(MM * EE / 8) / 256, 256, 0, stream>>>(parts, b2f, x1,
                                                          (float*)d_out);
}